// Round 14
// baseline (578.374 us; speedup 1.0000x reference)
//
#include <hip/hip_runtime.h>
#include <hip/hip_bf16.h>

#define TT 8
#define NN 10000
#define EE 320000
#define NG 64
#define SZH 384   // ZH fp16 row: 4 levels x 96 (h1[0,32) h2[32,48) x[48,80) pad[80,96))

typedef short v8s __attribute__((ext_vector_type(8)));
typedef _Float16 v8h __attribute__((ext_vector_type(8)));
typedef float v4f __attribute__((ext_vector_type(4)));

__device__ __forceinline__ float sigmf(float x){ return 1.f/(1.f+expf(-x)); }
__device__ __forceinline__ unsigned short f2h(float f){ _Float16 h=(_Float16)f; return __builtin_bit_cast(unsigned short,h); }
__device__ __forceinline__ float h2f(unsigned short s){ return (float)__builtin_bit_cast(_Float16,s); }
__device__ __forceinline__ unsigned pack2h(float x,float y){ return (unsigned)f2h(x) | ((unsigned)f2h(y)<<16); }
// fragment index: c = kt*32 + 8g + reg, m = row&15
__device__ __forceinline__ size_t fragidx(int TK,int row,int c){
  int tile=row>>4, m=row&15, kt=c>>5, cc=c&31;
  return ((size_t)(tile*TK+kt)*64 + (cc>>3)*16 + m)*8 + (cc&7);
}

// fetch original combined-K weights
__device__ __forceinline__ float fetchW1(const float* Wx, const float* Wh, int kk, int col){
  int g=col>>5, j=col&31;
  if(kk<160){ int k=kk>>5, i=kk&31; return Wx[((g*5+k)*32+i)*32+j]; }
  int rr=kk-160; int k=rr>>5, i=rr&31; return Wh[((g*5+k)*32+i)*32+j];
}
__device__ __forceinline__ float fetchW2(const float* Wx, const float* Wh, int kk, int col){
  int g=col>>4, j=col&15;
  if(kk<160){ int k=kk>>5, i=kk&31; return Wx[((g*5+k)*32+i)*16+j]; }
  if(kk<240){ int rr=kk-160; int k=rr>>4, i=rr&15; return Wh[((g*5+k)*16+i)*16+j]; }
  return 0.f;
}

// ---------- setup ----------
// merged: deg/cnt atomics (2-way shadow split) || W pack || x(0) init
__global__ void k_setup0(const int* __restrict__ src, const int* __restrict__ dst,
                         const float* __restrict__ ea, float* __restrict__ deg2, int* __restrict__ cnt2,
                         const float* __restrict__ Wx1,const float* __restrict__ bx1,
                         const float* __restrict__ Wh1,const float* __restrict__ bh1,const float* __restrict__ b1,
                         const float* __restrict__ Wx2,const float* __restrict__ bx2,
                         const float* __restrict__ Wh2,const float* __restrict__ bh2,const float* __restrict__ b2g,
                         short* __restrict__ Wpk1, short* __restrict__ Wpk2,
                         float* __restrict__ Bc1,float* __restrict__ Bc2,
                         const float* __restrict__ x, unsigned short* __restrict__ ZH, short* __restrict__ Zb1){
  int idx = blockIdx.x*256+threadIdx.x;
  if(idx<EE){
    int sh = (idx&1)*NN;
    atomicAdd(&deg2[sh+src[idx]], ea[idx]);
    atomicAdd(&cnt2[sh+dst[idx]], 1);
  }
  // W pack
  if(idx < 5120){
    int lane=idx&63, rest=idx>>6;
    int nt=rest&7, kt=rest>>3;
    int col = nt*16 + (lane&15);
    int g = lane>>4;
    #pragma unroll
    for(int j=0;j<8;j++){
      int kk = kt*32 + 8*g + j;
      Wpk1[(size_t)idx*8+j]=(short)f2h(fetchW1(Wx1,Wh1,kk,col));
    }
  } else if(idx < 7168){
    int t=idx-5120;
    int lane=t&63, rest=t>>6;
    int nt=rest&3, kt=rest>>2;
    int col = nt*16 + (lane&15);
    int g = lane>>4;
    #pragma unroll
    for(int j=0;j<8;j++){
      int kk = kt*32 + 8*g + j;
      Wpk2[(size_t)t*8+j]=(short)f2h(fetchW2(Wx2,Wh2,kk,col));
    }
  } else if(idx < 7296){
    int i=idx-7168; int g=i>>5,j=i&31;
    Bc1[i]=bx1[g*32+j]+bh1[g*32+j]+b1[g*32+j];
  } else if(idx < 7360){
    int i=idx-7296; int g=i>>4,j=i&15;
    Bc2[i]=bx2[g*16+j]+bh2[g*16+j]+b2g[g*16+j];
  }
  // x(0) init -> ZH level0 x-part + Zb1 kt0
  if(idx<NN*8){
    int n=idx>>3, c4=idx&7;
    float4 v = ((const float4*)x)[idx];
    unsigned p0=pack2h(v.x,v.y), p1=pack2h(v.z,v.w);
    *(unsigned*)&ZH[(size_t)n*SZH + 48 + c4*4]     = p0;
    *(unsigned*)&ZH[(size_t)n*SZH + 48 + c4*4 + 2] = p1;
    size_t fi = fragidx(5, n, c4*4);
    *(unsigned*)&Zb1[fi]   = p0;
    *(unsigned*)&Zb1[fi+2] = p1;
  }
}

// decoupled-lookback scan over cnt2 -> rowptr (inclusive at i+1), wp (exclusive); also reduces deg2 -> deg.
__global__ __launch_bounds__(1024) void k_scan2(const int* __restrict__ cnt2, int* __restrict__ rowptr,
                                                int* __restrict__ wp, int* __restrict__ lookback,
                                                const float* __restrict__ deg2, float* __restrict__ deg){
  __shared__ int wsum[16];
  __shared__ int blocksum_sh;
  __shared__ int prevsum_sh;
  int b=blockIdx.x, tid=threadIdx.x, lane=tid&63, wv=tid>>6;
  int i = b*1024 + tid;
  int v = (i<NN)? (cnt2[i]+cnt2[NN+i]) : 0;
  if(i<NN) deg[i] = deg2[i]+deg2[NN+i];
  int s=v;
  #pragma unroll
  for(int d=1;d<64;d<<=1){ int t=__shfl_up(s,d,64); if(lane>=d) s+=t; }
  if(lane==63) wsum[wv]=s;
  __syncthreads();
  if(wv==0 && lane<16){
    int t=wsum[lane]; int ss=t;
    #pragma unroll
    for(int d=1;d<16;d<<=1){ int u=__shfl_up(ss,d,64); if(lane>=d) ss+=u; }
    wsum[lane]=ss-t;  // exclusive prefix of wave sums
  }
  __syncthreads();
  int incl = wsum[wv] + s;     // block-local inclusive
  if(tid==1023) blocksum_sh = incl;
  __syncthreads();
  if(tid==0){
    int prev=0;
    if(b>0){
      while(true){ int f=atomicAdd(&lookback[b-1],0); if(f!=0){ prev=f-1; break; } }
    }
    atomicExch(&lookback[b], prev + blocksum_sh + 1);
    prevsum_sh = prev;
    if(b==0) rowptr[0]=0;
  }
  __syncthreads();
  int prev = prevsum_sh;
  if(i<NN){
    rowptr[i+1] = prev + incl;
    wp[i]       = prev + incl - v;
  }
}

// merged: dis (inline rsqrt) + wnorm + scatter. pack.x = pre-scaled src*SZH.
__global__ void k_wscatter(const int* __restrict__ src, const int* __restrict__ dst,
                           const float* __restrict__ ea, const float* __restrict__ deg,
                           int* __restrict__ wp, int2* __restrict__ pack){
  int e = blockIdx.x*256+threadIdx.x;
  if(e<EE){
    int s=src[e], d=dst[e];
    float ds_=deg[s], dd=deg[d];
    float is = ds_>0.f ? rsqrtf(ds_) : 0.f;
    float id = dd >0.f ? rsqrtf(dd ) : 0.f;
    float w = is*ea[e]*id;
    int pos = atomicAdd(&wp[d],1);
    pack[pos] = make_int2(s*SZH, __float_as_int(w));
  }
}

// ---------- per-timestep ----------
// One wave per node (uniform wid -> scalar pack loads); lane handles 2 fp16 channels.
// MODE 0 = x-only (16 lanes). MODE 1 = h1,h2,x (40 lanes). MODE 2 = h1,h2 (24 lanes).
template<int MODE>
__global__ __launch_bounds__(512) void k_spmm(const int* __restrict__ rowptr, const int2* __restrict__ pack,
    unsigned short* __restrict__ ZH,
    short* __restrict__ Zb1, short* __restrict__ Zb2, int k){
  int wlocal = __builtin_amdgcn_readfirstlane(threadIdx.x>>6);
  int wid = blockIdx.x*8 + wlocal;
  if(wid>=NN) return;
  int l = threadIdx.x&63;
  int ch; bool act;
  if(MODE==0){ ch=48+2*l; act=(l<16); }
  else if(MODE==1){
    if(l<16) ch=2*l; else if(l<24) ch=32+2*(l-16); else ch=48+2*(l-24);
    act=(l<40);
  } else {
    if(l<16) ch=2*l; else ch=32+2*(l-16);
    act=(l<24);
  }
  if(!act) ch=(MODE==2)?0:48;
  int cin_h = (k-1)*96 + ch;
  int base,width,cloc;
  if(ch<32){ base=0; width=32; cloc=ch; }
  else if(ch<48){ base=160; width=16; cloc=ch-32; }
  else { base=240; width=32; cloc=ch-48; }
  int cout = base + k*width + cloc;
  const unsigned short* __restrict__ Zc = ZH + cin_h;   // + pack.x (pre-scaled) = full addr
  int e0=rowptr[wid], e1=rowptr[wid+1];
  float accx=0.f, accy=0.f;
  int e=e0;
  for(; e+16<=e1; e+=16){
    float w[16]; unsigned z[16];
    #pragma unroll
    for(int j=0;j<16;j++){
      int2 p=pack[e+j];
      w[j]=__int_as_float(p.y);
      z[j]=*(const unsigned*)&Zc[(unsigned)p.x];
    }
    #pragma unroll
    for(int j=0;j<16;j++){
      accx = fmaf(h2f((unsigned short)(z[j]&0xffffu)), w[j], accx);
      accy = fmaf(h2f((unsigned short)(z[j]>>16)),     w[j], accy);
    }
  }
  for(; e+4<=e1; e+=4){
    float w[4]; unsigned z[4];
    #pragma unroll
    for(int j=0;j<4;j++){ int2 p=pack[e+j]; w[j]=__int_as_float(p.y); z[j]=*(const unsigned*)&Zc[(unsigned)p.x]; }
    #pragma unroll
    for(int j=0;j<4;j++){
      accx = fmaf(h2f((unsigned short)(z[j]&0xffffu)), w[j], accx);
      accy = fmaf(h2f((unsigned short)(z[j]>>16)),     w[j], accy);
    }
  }
  for(; e<e1; ++e){
    int2 p=pack[e];
    unsigned zz=*(const unsigned*)&Zc[(unsigned)p.x];
    float ww=__int_as_float(p.y);
    accx = fmaf(h2f((unsigned short)(zz&0xffffu)), ww, accx);
    accy = fmaf(h2f((unsigned short)(zz>>16)),     ww, accy);
  }
  if(act){
    float alpha=(k==1)?1.f:2.f;
    float vx = -alpha*accx, vy = -alpha*accy;
    if(k>=2){
      unsigned pp=*(const unsigned*)&ZH[(size_t)wid*SZH+(k-2)*96+ch];
      vx -= h2f((unsigned short)(pp&0xffffu));
      vy -= h2f((unsigned short)(pp>>16));
    }
    unsigned hh = pack2h(vx,vy);
    if(k<=3) *(unsigned*)&ZH[(size_t)wid*SZH + k*96 + ch] = hh;
    if(ch<48) *(unsigned*)&Zb2[fragidx(8,wid,cout)] = hh;
    else      *(unsigned*)&Zb1[fragidx(5,wid,cout-240)] = hh;
  }
}

// ---------- GEMM device bodies ----------
// gemm1(t): A = [T(x(t)) | T(h1(t-1))], K=320. h1(t-1) T0 from H1T0r; writes h1(t) T0 to H1T0w.
__device__ __forceinline__ void gemm1_dev(int tile,int lane,
        const short* __restrict__ Zb1, const short* __restrict__ Zb2,
        const v8s* __restrict__ H1T0r, v8s* __restrict__ H1T0w,
        const short* __restrict__ Wpk, const float* __restrict__ Bc, const float* __restrict__ wc1,
        float* __restrict__ c1, unsigned short* __restrict__ ZH,
        short* __restrict__ Zb1w, const float* __restrict__ xn){
  const v8s* A1=(const v8s*)Zb1 + (size_t)tile*320 + lane;
  const v8s* A2=(const v8s*)Zb2 + (size_t)tile*512 + lane;
  v8h afr[10];
  #pragma unroll
  for(int kt=0;kt<5;kt++) afr[kt]=__builtin_bit_cast(v8h, A1[kt*64]);
  afr[5]=__builtin_bit_cast(v8h, H1T0r[(size_t)tile*64+lane]);
  #pragma unroll
  for(int kt=1;kt<5;kt++) afr[5+kt]=__builtin_bit_cast(v8h, A2[kt*64]);
  const v8s* Wp=(const v8s*)Wpk;
  v4f acc[8];
  #pragma unroll
  for(int nt=0;nt<8;nt++) acc[nt]=(v4f){0.f,0.f,0.f,0.f};
  #pragma unroll
  for(int kt=0;kt<10;kt++){
    #pragma unroll
    for(int nt=0;nt<8;nt++){
      v8h b=__builtin_bit_cast(v8h, Wp[(kt*8+nt)*64+lane]);
      acc[nt]=__builtin_amdgcn_mfma_f32_16x16x32_f16(afr[kt],b,acc[nt],0,0,0);
    }
  }
  int row0=tile*16;
  int j0=lane&15;
  int r0=row0+(lane>>4)*4;
  #pragma unroll
  for(int reg=0;reg<4;reg++){
    int row=r0+reg;
    #pragma unroll
    for(int jj=0;jj<2;jj++){
      int j=jj*16+j0;
      float c=c1[row*32+j];
      float I =sigmf(acc[0+jj][reg]+Bc[j]      + wc1[j]*c);
      float Fg=sigmf(acc[2+jj][reg]+Bc[32+j]   + wc1[32+j]*c);
      float Ct=tanhf(acc[4+jj][reg]+Bc[64+j]);
      float Cn=Fg*c + I*Ct;
      float O =sigmf(acc[6+jj][reg]+Bc[96+j]   + wc1[64+j]*Cn);
      float h =O*tanhf(Cn);
      c1[row*32+j]=Cn;
      ZH[(size_t)row*SZH + j]=f2h(h);
      ((unsigned short*)H1T0w)[fragidx(1,row,j)]=f2h(h);
    }
    if(xn){
      float2 xv=*(const float2*)&xn[(size_t)row*32 + 2*j0];
      unsigned pr=pack2h(xv.x,xv.y);
      *(unsigned*)&ZH[(size_t)row*SZH + 48 + 2*j0]=pr;
      *(unsigned*)&Zb1w[fragidx(5,row,2*j0)]=pr;
    }
  }
}

// gemm2(t): A kt0 = h1(t) T0 from H1T0r, kt1..7 from Zb2.
__device__ __forceinline__ void gemm2_dev(int tile,int lane,
        const short* __restrict__ Zb2, const v8s* __restrict__ H1T0r,
        const short* __restrict__ Wpk, const float* __restrict__ Bc, const float* __restrict__ wc2,
        float* __restrict__ c2, unsigned short* __restrict__ ZH,
        short* __restrict__ Zb2w, float* __restrict__ u, const int* __restrict__ batch, int last){
  const v8s* Az=(const v8s*)Zb2 + (size_t)tile*512 + lane;
  v8h afr[8];
  afr[0]=__builtin_bit_cast(v8h, H1T0r[(size_t)tile*64+lane]);
  #pragma unroll
  for(int kt=1;kt<8;kt++) afr[kt]=__builtin_bit_cast(v8h, Az[kt*64]);
  const v8s* Wp=(const v8s*)Wpk;
  v4f acc[4];
  #pragma unroll
  for(int nt=0;nt<4;nt++) acc[nt]=(v4f){0.f,0.f,0.f,0.f};
  #pragma unroll
  for(int kt=0;kt<8;kt++){
    #pragma unroll
    for(int nt=0;nt<4;nt++){
      v8h b=__builtin_bit_cast(v8h, Wp[(kt*4+nt)*64+lane]);
      acc[nt]=__builtin_amdgcn_mfma_f32_16x16x32_f16(afr[kt],b,acc[nt],0,0,0);
    }
  }
  int row0=tile*16;
  int j=lane&15;
  int r0=row0+(lane>>4)*4;
  #pragma unroll
  for(int reg=0;reg<4;reg++){
    int row=r0+reg;
    float c=c2[row*16+j];
    float I =sigmf(acc[0][reg]+Bc[j]    +wc2[j]*c);
    float Fg=sigmf(acc[1][reg]+Bc[16+j] +wc2[16+j]*c);
    float Ct=tanhf(acc[2][reg]+Bc[32+j]);
    float Cn=Fg*c+I*Ct;
    float O =sigmf(acc[3][reg]+Bc[48+j] +wc2[32+j]*Cn);
    float h =O*tanhf(Cn);
    c2[row*16+j]=Cn;
    ZH[(size_t)row*SZH + 32 + j]=f2h(h);
    Zb2w[fragidx(8,row,160+j)]=(short)f2h(h);
    if(last) atomicAdd(&u[batch[row]*16+j], h);
  }
}

// ---------- GEMM kernels (1-wave blocks) ----------
__global__ __launch_bounds__(64) void k_g1(const short* Zb1, const short* Zb2,
        const v8s* H1T0r, v8s* H1T0w, const short* Wpk1, const float* Bc1, const float* wc1,
        float* c1, unsigned short* ZH, short* Zb1w, const float* xn){
  gemm1_dev(blockIdx.x,threadIdx.x,Zb1,Zb2,H1T0r,H1T0w,Wpk1,Bc1,wc1,c1,ZH,Zb1w,xn);
}

// merged: blocks [0,625) -> gemm1(t+1); [625,1250) -> gemm2(t)
__global__ __launch_bounds__(64) void k_g12(const short* Zb1, const short* Zb2,
        const v8s* H1T0r, v8s* H1T0w,
        const short* Wpk1, const float* Bc1, const float* wc1, float* c1,
        const short* Wpk2, const float* Bc2, const float* wc2, float* c2,
        unsigned short* ZH, short* Zb1w, short* Zb2w,
        const float* xn, float* u, const int* batch){
  int b=blockIdx.x, lane=threadIdx.x;
  if(b<625) gemm1_dev(b,lane,Zb1,Zb2,H1T0r,H1T0w,Wpk1,Bc1,wc1,c1,ZH,Zb1w,xn);
  else      gemm2_dev(b-625,lane,Zb2,H1T0r,Wpk2,Bc2,wc2,c2,ZH,Zb2w,u,batch,0);
}

// last gemm2 + pool + fused finale (ticketed)
__global__ __launch_bounds__(64) void k_g2f(const short* Zb2, const v8s* H1T0r,
        const short* Wpk2, const float* Bc2, const float* wc2,
        float* c2, unsigned short* ZH, short* Zb2w,
        float* u, const int* batch, int* ticket,
        const float* lw, const float* lb, float* out){
  int lane=threadIdx.x;
  gemm2_dev(blockIdx.x,lane,Zb2,H1T0r,Wpk2,Bc2,wc2,c2,ZH,Zb2w,u,batch,1);
  __threadfence();
  __shared__ int tk;
  if(lane==0) tk = atomicAdd(ticket,1);
  __syncthreads();
  if(tk==624 && lane<NG){
    float s=lb[0];
    #pragma unroll
    for(int j=0;j<16;j++) s += atomicAdd(&u[lane*16+j],0.f)*lw[j];
    out[lane]=s;
  }
}

extern "C" void kernel_launch(void* const* d_in, const int* in_sizes, int n_in,
                              void* d_out, int out_size, void* d_ws, size_t ws_size,
                              hipStream_t stream){
  const float* x   = (const float*)d_in[0];
  const int*   ei  = (const int*)d_in[1];
  const float* ea  = (const float*)d_in[2];
  const int*   bat = (const int*)d_in[3];
  const float* Wx1=(const float*)d_in[4];  const float* bx1=(const float*)d_in[5];
  const float* Wh1=(const float*)d_in[6];  const float* bh1=(const float*)d_in[7];
  const float* wc1=(const float*)d_in[8];  const float* b1 =(const float*)d_in[9];
  const float* Wx2=(const float*)d_in[10]; const float* bx2=(const float*)d_in[11];
  const float* Wh2=(const float*)d_in[12]; const float* bh2=(const float*)d_in[13];
  const float* wc2=(const float*)d_in[14]; const float* b2 =(const float*)d_in[15];
  const float* lw =(const float*)d_in[16]; const float* lb =(const float*)d_in[17];
  const int* src = ei; const int* dst = ei+EE;

  float* ws = (float*)d_ws;
  size_t off=0;
  auto alloc=[&](size_t n)->float*{ float* p=ws+off; off+=(n+15)&~(size_t)15; return p; };
  // zeroed region: deg2(2NN), c1, c2, u, cnt2(2NN), lookback, ticket, ZH, Zb1, Zb2, H1T0[2]
  float* deg2=alloc(2*NN);
  float* c1=alloc((size_t)NN*32);
  float* c2=alloc((size_t)NN*16);
  float* u =alloc(NG*16);
  int*   cnt2=(int*)alloc(2*NN);
  int*   lookback=(int*)alloc(16);
  int*   ticket=(int*)alloc(16);
  unsigned short* ZH=(unsigned short*)alloc((size_t)NN*SZH/2);
  short* Zb1=(short*)alloc(625*5*64*8/2);
  short* Zb2=(short*)alloc(625*8*64*8/2);
  short* H1T0a=(short*)alloc(625*64*8/2);
  short* H1T0b=(short*)alloc(625*64*8/2);
  size_t zeroEnd=off;
  float* deg=alloc(NN);
  int*   rowptr=(int*)alloc(NN+1);
  int*   wp=(int*)alloc(NN);
  int2*  pack=(int2*)alloc((size_t)EE*2);
  short* Wpk1=(short*)alloc(5120*4);
  short* Wpk2=(short*)alloc(2048*4);
  float* Bc1=alloc(128);     float* Bc2=alloc(64);
  (void)ws_size; (void)in_sizes; (void)n_in; (void)out_size;
  v8s* H1T0[2] = { (v8s*)H1T0a, (v8s*)H1T0b };

  hipMemsetAsync(d_ws, 0, zeroEnd*sizeof(float), stream);
  k_setup0  <<<1250,256,0,stream>>>(src,dst,ea,deg2,cnt2,
      Wx1,bx1,Wh1,bh1,b1,Wx2,bx2,Wh2,bh2,b2,Wpk1,Wpk2,Bc1,Bc2, x,ZH,Zb1);
  k_scan2   <<<10,1024,0,stream>>>(cnt2,rowptr,wp,lookback,deg2,deg);
  k_wscatter<<<1250,256,0,stream>>>(src,dst,ea,deg,wp,pack);

  for(int k=1;k<5;k++)
    k_spmm<0><<<1250,512,0,stream>>>(rowptr,pack,ZH,Zb1,Zb2,k);   // T_k(x(0))

  // gemm1(t=0): reads H1T0[1] (zeros = h1(-1)); writes H1T0[0]; copies x(1)
  k_g1<<<625,64,0,stream>>>(Zb1,Zb2,H1T0[1],H1T0[0],Wpk1,Bc1,wc1,c1,ZH,Zb1, x+(size_t)NN*32);

  for(int t=0;t<TT-1;t++){
    for(int k=1;k<5;k++)
      k_spmm<1><<<1250,512,0,stream>>>(rowptr,pack,ZH,Zb1,Zb2,k);  // T_k(h1(t)), T_k(h2(t-1)), T_k(x(t+1))
    // merged: gemm1(t+1) || gemm2(t)
    k_g12<<<1250,64,0,stream>>>(Zb1,Zb2,H1T0[t&1],H1T0[(t+1)&1],
        Wpk1,Bc1,wc1,c1, Wpk2,Bc2,wc2,c2, ZH,Zb1,Zb2,
        (t+2<TT)? x+(size_t)(t+2)*NN*32 : nullptr, u,bat);
  }
  // t = TT-1: chains of h1(7), h2(6); then gemm2(7) + pool + finale
  for(int k=1;k<5;k++)
    k_spmm<2><<<1250,512,0,stream>>>(rowptr,pack,ZH,Zb1,Zb2,k);
  k_g2f<<<625,64,0,stream>>>(Zb2,H1T0[(TT-1)&1],Wpk2,Bc2,wc2,c2,ZH,Zb2,u,bat,ticket,lw,lb,(float*)d_out);
}

// Round 15
// 567.878 us; speedup vs baseline: 1.0185x; 1.0185x over previous
//
#include <hip/hip_runtime.h>
#include <hip/hip_bf16.h>

#define TT 8
#define NN 10000
#define EE 320000
#define NG 64
#define SZH 384   // ZH fp16 row: 4 levels x 96 (h1[0,32) h2[32,48) x[48,80) pad[80,96))

typedef short v8s __attribute__((ext_vector_type(8)));
typedef _Float16 v8h __attribute__((ext_vector_type(8)));
typedef float v4f __attribute__((ext_vector_type(4)));

__device__ __forceinline__ float sigmf(float x){ return 1.f/(1.f+expf(-x)); }
__device__ __forceinline__ unsigned short f2h(float f){ _Float16 h=(_Float16)f; return __builtin_bit_cast(unsigned short,h); }
__device__ __forceinline__ float h2f(unsigned short s){ return (float)__builtin_bit_cast(_Float16,s); }
__device__ __forceinline__ unsigned pack2h(float x,float y){ return (unsigned)f2h(x) | ((unsigned)f2h(y)<<16); }
// fragment index: c = kt*32 + 8g + reg, m = row&15
__device__ __forceinline__ size_t fragidx(int TK,int row,int c){
  int tile=row>>4, m=row&15, kt=c>>5, cc=c&31;
  return ((size_t)(tile*TK+kt)*64 + (cc>>3)*16 + m)*8 + (cc&7);
}

// fetch original combined-K weights
__device__ __forceinline__ float fetchW1(const float* Wx, const float* Wh, int kk, int col){
  int g=col>>5, j=col&31;
  if(kk<160){ int k=kk>>5, i=kk&31; return Wx[((g*5+k)*32+i)*32+j]; }
  int rr=kk-160; int k=rr>>5, i=rr&31; return Wh[((g*5+k)*32+i)*32+j];
}
__device__ __forceinline__ float fetchW2(const float* Wx, const float* Wh, int kk, int col){
  int g=col>>4, j=col&15;
  if(kk<160){ int k=kk>>5, i=kk&31; return Wx[((g*5+k)*32+i)*16+j]; }
  if(kk<240){ int rr=kk-160; int k=rr>>4, i=rr&15; return Wh[((g*5+k)*16+i)*16+j]; }
  return 0.f;
}

// ---------- setup ----------
// merged: deg/cnt atomics (4-way shadow split) || W pack || x(0) init
__global__ void k_setup0(const int* __restrict__ src, const int* __restrict__ dst,
                         const float* __restrict__ ea, float* __restrict__ deg4, int* __restrict__ cnt4,
                         const float* __restrict__ Wx1,const float* __restrict__ bx1,
                         const float* __restrict__ Wh1,const float* __restrict__ bh1,const float* __restrict__ b1,
                         const float* __restrict__ Wx2,const float* __restrict__ bx2,
                         const float* __restrict__ Wh2,const float* __restrict__ bh2,const float* __restrict__ b2g,
                         short* __restrict__ Wpk1, short* __restrict__ Wpk2,
                         float* __restrict__ Bc1,float* __restrict__ Bc2,
                         const float* __restrict__ x, unsigned short* __restrict__ ZH, short* __restrict__ Zb1){
  int idx = blockIdx.x*256+threadIdx.x;
  if(idx<EE){
    int sh = (idx&3)*NN;
    atomicAdd(&deg4[sh+src[idx]], ea[idx]);
    atomicAdd(&cnt4[sh+dst[idx]], 1);
  }
  // W pack
  if(idx < 5120){
    int lane=idx&63, rest=idx>>6;
    int nt=rest&7, kt=rest>>3;
    int col = nt*16 + (lane&15);
    int g = lane>>4;
    #pragma unroll
    for(int j=0;j<8;j++){
      int kk = kt*32 + 8*g + j;
      Wpk1[(size_t)idx*8+j]=(short)f2h(fetchW1(Wx1,Wh1,kk,col));
    }
  } else if(idx < 7168){
    int t=idx-5120;
    int lane=t&63, rest=t>>6;
    int nt=rest&3, kt=rest>>2;
    int col = nt*16 + (lane&15);
    int g = lane>>4;
    #pragma unroll
    for(int j=0;j<8;j++){
      int kk = kt*32 + 8*g + j;
      Wpk2[(size_t)t*8+j]=(short)f2h(fetchW2(Wx2,Wh2,kk,col));
    }
  } else if(idx < 7296){
    int i=idx-7168; int g=i>>5,j=i&31;
    Bc1[i]=bx1[g*32+j]+bh1[g*32+j]+b1[g*32+j];
  } else if(idx < 7360){
    int i=idx-7296; int g=i>>4,j=i&15;
    Bc2[i]=bx2[g*16+j]+bh2[g*16+j]+b2g[g*16+j];
  }
  // x(0) init -> ZH level0 x-part + Zb1 kt0
  if(idx<NN*8){
    int n=idx>>3, c4=idx&7;
    float4 v = ((const float4*)x)[idx];
    unsigned p0=pack2h(v.x,v.y), p1=pack2h(v.z,v.w);
    *(unsigned*)&ZH[(size_t)n*SZH + 48 + c4*4]     = p0;
    *(unsigned*)&ZH[(size_t)n*SZH + 48 + c4*4 + 2] = p1;
    size_t fi = fragidx(5, n, c4*4);
    *(unsigned*)&Zb1[fi]   = p0;
    *(unsigned*)&Zb1[fi+2] = p1;
  }
}

// decoupled-lookback scan over cnt4 -> rowptr (inclusive at i+1), wp (exclusive); also reduces deg4 -> deg.
__global__ __launch_bounds__(1024) void k_scan2(const int* __restrict__ cnt4, int* __restrict__ rowptr,
                                                int* __restrict__ wp, int* __restrict__ lookback,
                                                const float* __restrict__ deg4, float* __restrict__ deg){
  __shared__ int wsum[16];
  __shared__ int blocksum_sh;
  __shared__ int prevsum_sh;
  int b=blockIdx.x, tid=threadIdx.x, lane=tid&63, wv=tid>>6;
  int i = b*1024 + tid;
  int v = (i<NN)? (cnt4[i]+cnt4[NN+i]+cnt4[2*NN+i]+cnt4[3*NN+i]) : 0;
  if(i<NN) deg[i] = deg4[i]+deg4[NN+i]+deg4[2*NN+i]+deg4[3*NN+i];
  int s=v;
  #pragma unroll
  for(int d=1;d<64;d<<=1){ int t=__shfl_up(s,d,64); if(lane>=d) s+=t; }
  if(lane==63) wsum[wv]=s;
  __syncthreads();
  if(wv==0 && lane<16){
    int t=wsum[lane]; int ss=t;
    #pragma unroll
    for(int d=1;d<16;d<<=1){ int u=__shfl_up(ss,d,64); if(lane>=d) ss+=u; }
    wsum[lane]=ss-t;  // exclusive prefix of wave sums
  }
  __syncthreads();
  int incl = wsum[wv] + s;     // block-local inclusive
  if(tid==1023) blocksum_sh = incl;
  __syncthreads();
  if(tid==0){
    int prev=0;
    if(b>0){
      while(true){ int f=atomicAdd(&lookback[b-1],0); if(f!=0){ prev=f-1; break; } }
    }
    atomicExch(&lookback[b], prev + blocksum_sh + 1);
    prevsum_sh = prev;
    if(b==0) rowptr[0]=0;
  }
  __syncthreads();
  int prev = prevsum_sh;
  if(i<NN){
    rowptr[i+1] = prev + incl;
    wp[i]       = prev + incl - v;
  }
}

// merged: dis (inline rsqrt) + wnorm + scatter. pack.x = pre-scaled src*SZH.
__global__ void k_wscatter(const int* __restrict__ src, const int* __restrict__ dst,
                           const float* __restrict__ ea, const float* __restrict__ deg,
                           int* __restrict__ wp, int2* __restrict__ pack){
  int e = blockIdx.x*256+threadIdx.x;
  if(e<EE){
    int s=src[e], d=dst[e];
    float ds_=deg[s], dd=deg[d];
    float is = ds_>0.f ? rsqrtf(ds_) : 0.f;
    float id = dd >0.f ? rsqrtf(dd ) : 0.f;
    float w = is*ea[e]*id;
    int pos = atomicAdd(&wp[d],1);
    pack[pos] = make_int2(s*SZH, __float_as_int(w));
  }
}

// ---------- per-timestep ----------
// One wave per node (uniform wid -> scalar pack loads); lane handles 2 fp16 channels.
// MODE 0 = x-only (16 lanes). MODE 1 = h1,h2,x (40 lanes). MODE 2 = h1,h2 (24 lanes).
template<int MODE>
__global__ __launch_bounds__(512) void k_spmm(const int* __restrict__ rowptr, const int2* __restrict__ pack,
    unsigned short* __restrict__ ZH,
    short* __restrict__ Zb1, short* __restrict__ Zb2, int k){
  int wlocal = __builtin_amdgcn_readfirstlane(threadIdx.x>>6);
  int wid = blockIdx.x*8 + wlocal;
  if(wid>=NN) return;
  int l = threadIdx.x&63;
  int ch; bool act;
  if(MODE==0){ ch=48+2*l; act=(l<16); }
  else if(MODE==1){
    if(l<16) ch=2*l; else if(l<24) ch=32+2*(l-16); else ch=48+2*(l-24);
    act=(l<40);
  } else {
    if(l<16) ch=2*l; else ch=32+2*(l-16);
    act=(l<24);
  }
  if(!act) ch=(MODE==2)?0:48;
  int cin_h = (k-1)*96 + ch;
  int base,width,cloc;
  if(ch<32){ base=0; width=32; cloc=ch; }
  else if(ch<48){ base=160; width=16; cloc=ch-32; }
  else { base=240; width=32; cloc=ch-48; }
  int cout = base + k*width + cloc;
  const unsigned short* __restrict__ Zc = ZH + cin_h;   // + pack.x (pre-scaled) = full addr
  int e0=rowptr[wid], e1=rowptr[wid+1];
  float accx=0.f, accy=0.f;
  int e=e0;
  for(; e+16<=e1; e+=16){
    float w[16]; unsigned z[16];
    #pragma unroll
    for(int j=0;j<16;j++){
      int2 p=pack[e+j];
      w[j]=__int_as_float(p.y);
      z[j]=*(const unsigned*)&Zc[(unsigned)p.x];
    }
    #pragma unroll
    for(int j=0;j<16;j++){
      accx = fmaf(h2f((unsigned short)(z[j]&0xffffu)), w[j], accx);
      accy = fmaf(h2f((unsigned short)(z[j]>>16)),     w[j], accy);
    }
  }
  for(; e+4<=e1; e+=4){
    float w[4]; unsigned z[4];
    #pragma unroll
    for(int j=0;j<4;j++){ int2 p=pack[e+j]; w[j]=__int_as_float(p.y); z[j]=*(const unsigned*)&Zc[(unsigned)p.x]; }
    #pragma unroll
    for(int j=0;j<4;j++){
      accx = fmaf(h2f((unsigned short)(z[j]&0xffffu)), w[j], accx);
      accy = fmaf(h2f((unsigned short)(z[j]>>16)),     w[j], accy);
    }
  }
  for(; e<e1; ++e){
    int2 p=pack[e];
    unsigned zz=*(const unsigned*)&Zc[(unsigned)p.x];
    float ww=__int_as_float(p.y);
    accx = fmaf(h2f((unsigned short)(zz&0xffffu)), ww, accx);
    accy = fmaf(h2f((unsigned short)(zz>>16)),     ww, accy);
  }
  if(act){
    float alpha=(k==1)?1.f:2.f;
    float vx = -alpha*accx, vy = -alpha*accy;
    if(k>=2){
      unsigned pp=*(const unsigned*)&ZH[(size_t)wid*SZH+(k-2)*96+ch];
      vx -= h2f((unsigned short)(pp&0xffffu));
      vy -= h2f((unsigned short)(pp>>16));
    }
    unsigned hh = pack2h(vx,vy);
    if(k<=3) *(unsigned*)&ZH[(size_t)wid*SZH + k*96 + ch] = hh;
    if(ch<48) *(unsigned*)&Zb2[fragidx(8,wid,cout)] = hh;
    else      *(unsigned*)&Zb1[fragidx(5,wid,cout-240)] = hh;
  }
}

// ---------- GEMM device bodies ----------
// gemm1(t): A = [T(x(t)) | T(h1(t-1))], K=320. h1(t-1) T0 from H1T0r; writes h1(t) T0 to H1T0w.
__device__ __forceinline__ void gemm1_dev(int tile,int lane,
        const short* __restrict__ Zb1, const short* __restrict__ Zb2,
        const v8s* __restrict__ H1T0r, v8s* __restrict__ H1T0w,
        const short* __restrict__ Wpk, const float* __restrict__ Bc, const float* __restrict__ wc1,
        float* __restrict__ c1, unsigned short* __restrict__ ZH,
        short* __restrict__ Zb1w, const float* __restrict__ xn){
  const v8s* A1=(const v8s*)Zb1 + (size_t)tile*320 + lane;
  const v8s* A2=(const v8s*)Zb2 + (size_t)tile*512 + lane;
  v8h afr[10];
  #pragma unroll
  for(int kt=0;kt<5;kt++) afr[kt]=__builtin_bit_cast(v8h, A1[kt*64]);
  afr[5]=__builtin_bit_cast(v8h, H1T0r[(size_t)tile*64+lane]);
  #pragma unroll
  for(int kt=1;kt<5;kt++) afr[5+kt]=__builtin_bit_cast(v8h, A2[kt*64]);
  const v8s* Wp=(const v8s*)Wpk;
  v4f acc[8];
  #pragma unroll
  for(int nt=0;nt<8;nt++) acc[nt]=(v4f){0.f,0.f,0.f,0.f};
  #pragma unroll
  for(int kt=0;kt<10;kt++){
    #pragma unroll
    for(int nt=0;nt<8;nt++){
      v8h b=__builtin_bit_cast(v8h, Wp[(kt*8+nt)*64+lane]);
      acc[nt]=__builtin_amdgcn_mfma_f32_16x16x32_f16(afr[kt],b,acc[nt],0,0,0);
    }
  }
  int row0=tile*16;
  int j0=lane&15;
  int r0=row0+(lane>>4)*4;
  #pragma unroll
  for(int reg=0;reg<4;reg++){
    int row=r0+reg;
    #pragma unroll
    for(int jj=0;jj<2;jj++){
      int j=jj*16+j0;
      float c=c1[row*32+j];
      float I =sigmf(acc[0+jj][reg]+Bc[j]      + wc1[j]*c);
      float Fg=sigmf(acc[2+jj][reg]+Bc[32+j]   + wc1[32+j]*c);
      float Ct=tanhf(acc[4+jj][reg]+Bc[64+j]);
      float Cn=Fg*c + I*Ct;
      float O =sigmf(acc[6+jj][reg]+Bc[96+j]   + wc1[64+j]*Cn);
      float h =O*tanhf(Cn);
      c1[row*32+j]=Cn;
      ZH[(size_t)row*SZH + j]=f2h(h);
      ((unsigned short*)H1T0w)[fragidx(1,row,j)]=f2h(h);
    }
    if(xn){
      float2 xv=*(const float2*)&xn[(size_t)row*32 + 2*j0];
      unsigned pr=pack2h(xv.x,xv.y);
      *(unsigned*)&ZH[(size_t)row*SZH + 48 + 2*j0]=pr;
      *(unsigned*)&Zb1w[fragidx(5,row,2*j0)]=pr;
    }
  }
}

// gemm2(t): A kt0 = h1(t) T0 from H1T0r, kt1..7 from Zb2.
__device__ __forceinline__ void gemm2_dev(int tile,int lane,
        const short* __restrict__ Zb2, const v8s* __restrict__ H1T0r,
        const short* __restrict__ Wpk, const float* __restrict__ Bc, const float* __restrict__ wc2,
        float* __restrict__ c2, unsigned short* __restrict__ ZH,
        short* __restrict__ Zb2w, float* __restrict__ u, const int* __restrict__ batch, int last){
  const v8s* Az=(const v8s*)Zb2 + (size_t)tile*512 + lane;
  v8h afr[8];
  afr[0]=__builtin_bit_cast(v8h, H1T0r[(size_t)tile*64+lane]);
  #pragma unroll
  for(int kt=1;kt<8;kt++) afr[kt]=__builtin_bit_cast(v8h, Az[kt*64]);
  const v8s* Wp=(const v8s*)Wpk;
  v4f acc[4];
  #pragma unroll
  for(int nt=0;nt<4;nt++) acc[nt]=(v4f){0.f,0.f,0.f,0.f};
  #pragma unroll
  for(int kt=0;kt<8;kt++){
    #pragma unroll
    for(int nt=0;nt<4;nt++){
      v8h b=__builtin_bit_cast(v8h, Wp[(kt*4+nt)*64+lane]);
      acc[nt]=__builtin_amdgcn_mfma_f32_16x16x32_f16(afr[kt],b,acc[nt],0,0,0);
    }
  }
  int row0=tile*16;
  int j=lane&15;
  int r0=row0+(lane>>4)*4;
  #pragma unroll
  for(int reg=0;reg<4;reg++){
    int row=r0+reg;
    float c=c2[row*16+j];
    float I =sigmf(acc[0][reg]+Bc[j]    +wc2[j]*c);
    float Fg=sigmf(acc[1][reg]+Bc[16+j] +wc2[16+j]*c);
    float Ct=tanhf(acc[2][reg]+Bc[32+j]);
    float Cn=Fg*c+I*Ct;
    float O =sigmf(acc[3][reg]+Bc[48+j] +wc2[32+j]*Cn);
    float h =O*tanhf(Cn);
    c2[row*16+j]=Cn;
    ZH[(size_t)row*SZH + 32 + j]=f2h(h);
    Zb2w[fragidx(8,row,160+j)]=(short)f2h(h);
    if(last) atomicAdd(&u[batch[row]*16+j], h);
  }
}

// ---------- GEMM kernels (4-wave 256-thd blocks, r13 shape) ----------
__global__ __launch_bounds__(256) void k_g1(const short* Zb1, const short* Zb2,
        const v8s* H1T0r, v8s* H1T0w, const short* Wpk1, const float* Bc1, const float* wc1,
        float* c1, unsigned short* ZH, short* Zb1w, const float* xn){
  int wv=threadIdx.x>>6, lane=threadIdx.x&63;
  int tile=blockIdx.x*4+wv;
  if(tile>=625) return;
  gemm1_dev(tile,lane,Zb1,Zb2,H1T0r,H1T0w,Wpk1,Bc1,wc1,c1,ZH,Zb1w,xn);
}

// merged: blocks [0,157) -> gemm1(t+1); blocks [157,314) -> gemm2(t)
__global__ __launch_bounds__(256) void k_g12(const short* Zb1, const short* Zb2,
        const v8s* H1T0r, v8s* H1T0w,
        const short* Wpk1, const float* Bc1, const float* wc1, float* c1,
        const short* Wpk2, const float* Bc2, const float* wc2, float* c2,
        unsigned short* ZH, short* Zb1w, short* Zb2w,
        const float* xn, float* u, const int* batch){
  int wv=threadIdx.x>>6, lane=threadIdx.x&63;
  if(blockIdx.x<157){
    int tile=blockIdx.x*4+wv;
    if(tile>=625) return;
    gemm1_dev(tile,lane,Zb1,Zb2,H1T0r,H1T0w,Wpk1,Bc1,wc1,c1,ZH,Zb1w,xn);
  } else {
    int tile=(blockIdx.x-157)*4+wv;
    if(tile>=625) return;
    gemm2_dev(tile,lane,Zb2,H1T0r,Wpk2,Bc2,wc2,c2,ZH,Zb2w,u,batch,0);
  }
}

// last gemm2 + pool + fused finale (ticketed, barrier-safe: no early returns)
__global__ __launch_bounds__(256) void k_g2f(const short* Zb2, const v8s* H1T0r,
        const short* Wpk2, const float* Bc2, const float* wc2,
        float* c2, unsigned short* ZH, short* Zb2w,
        float* u, const int* batch, int* ticket,
        const float* lw, const float* lb, float* out){
  int wv=threadIdx.x>>6, lane=threadIdx.x&63;
  int tile=blockIdx.x*4+wv;
  if(tile<625) gemm2_dev(tile,lane,Zb2,H1T0r,Wpk2,Bc2,wc2,c2,ZH,Zb2w,u,batch,1);
  __threadfence();
  __syncthreads();
  __shared__ int tk;
  if(threadIdx.x==0) tk = atomicAdd(ticket,1);
  __syncthreads();
  if(tk==156 && threadIdx.x<NG){
    int g=threadIdx.x;
    float s=lb[0];
    #pragma unroll
    for(int j=0;j<16;j++) s += atomicAdd(&u[g*16+j],0.f)*lw[j];
    out[g]=s;
  }
}

extern "C" void kernel_launch(void* const* d_in, const int* in_sizes, int n_in,
                              void* d_out, int out_size, void* d_ws, size_t ws_size,
                              hipStream_t stream){
  const float* x   = (const float*)d_in[0];
  const int*   ei  = (const int*)d_in[1];
  const float* ea  = (const float*)d_in[2];
  const int*   bat = (const int*)d_in[3];
  const float* Wx1=(const float*)d_in[4];  const float* bx1=(const float*)d_in[5];
  const float* Wh1=(const float*)d_in[6];  const float* bh1=(const float*)d_in[7];
  const float* wc1=(const float*)d_in[8];  const float* b1 =(const float*)d_in[9];
  const float* Wx2=(const float*)d_in[10]; const float* bx2=(const float*)d_in[11];
  const float* Wh2=(const float*)d_in[12]; const float* bh2=(const float*)d_in[13];
  const float* wc2=(const float*)d_in[14]; const float* b2 =(const float*)d_in[15];
  const float* lw =(const float*)d_in[16]; const float* lb =(const float*)d_in[17];
  const int* src = ei; const int* dst = ei+EE;

  float* ws = (float*)d_ws;
  size_t off=0;
  auto alloc=[&](size_t n)->float*{ float* p=ws+off; off+=(n+15)&~(size_t)15; return p; };
  // zeroed region: deg4(4NN), c1, c2, u, cnt4(4NN), lookback, ticket, ZH, Zb1, Zb2, H1T0[2]
  float* deg4=alloc(4*NN);
  float* c1=alloc((size_t)NN*32);
  float* c2=alloc((size_t)NN*16);
  float* u =alloc(NG*16);
  int*   cnt4=(int*)alloc(4*NN);
  int*   lookback=(int*)alloc(16);
  int*   ticket=(int*)alloc(16);
  unsigned short* ZH=(unsigned short*)alloc((size_t)NN*SZH/2);
  short* Zb1=(short*)alloc(625*5*64*8/2);
  short* Zb2=(short*)alloc(625*8*64*8/2);
  short* H1T0a=(short*)alloc(625*64*8/2);
  short* H1T0b=(short*)alloc(625*64*8/2);
  size_t zeroEnd=off;
  float* deg=alloc(NN);
  int*   rowptr=(int*)alloc(NN+1);
  int*   wp=(int*)alloc(NN);
  int2*  pack=(int2*)alloc((size_t)EE*2);
  short* Wpk1=(short*)alloc(5120*4);
  short* Wpk2=(short*)alloc(2048*4);
  float* Bc1=alloc(128);     float* Bc2=alloc(64);
  (void)ws_size; (void)in_sizes; (void)n_in; (void)out_size;
  v8s* H1T0[2] = { (v8s*)H1T0a, (v8s*)H1T0b };

  hipMemsetAsync(d_ws, 0, zeroEnd*sizeof(float), stream);
  k_setup0  <<<1250,256,0,stream>>>(src,dst,ea,deg4,cnt4,
      Wx1,bx1,Wh1,bh1,b1,Wx2,bx2,Wh2,bh2,b2,Wpk1,Wpk2,Bc1,Bc2, x,ZH,Zb1);
  k_scan2   <<<10,1024,0,stream>>>(cnt4,rowptr,wp,lookback,deg4,deg);
  k_wscatter<<<1250,256,0,stream>>>(src,dst,ea,deg,wp,pack);

  for(int k=1;k<5;k++)
    k_spmm<0><<<1250,512,0,stream>>>(rowptr,pack,ZH,Zb1,Zb2,k);   // T_k(x(0))

  // gemm1(t=0): reads H1T0[1] (zeros = h1(-1)); writes H1T0[0]; copies x(1)
  k_g1<<<157,256,0,stream>>>(Zb1,Zb2,H1T0[1],H1T0[0],Wpk1,Bc1,wc1,c1,ZH,Zb1, x+(size_t)NN*32);

  for(int t=0;t<TT-1;t++){
    for(int k=1;k<5;k++)
      k_spmm<1><<<1250,512,0,stream>>>(rowptr,pack,ZH,Zb1,Zb2,k);  // T_k(h1(t)), T_k(h2(t-1)), T_k(x(t+1))
    // merged: gemm1(t+1) || gemm2(t)
    k_g12<<<314,256,0,stream>>>(Zb1,Zb2,H1T0[t&1],H1T0[(t+1)&1],
        Wpk1,Bc1,wc1,c1, Wpk2,Bc2,wc2,c2, ZH,Zb1,Zb2,
        (t+2<TT)? x+(size_t)(t+2)*NN*32 : nullptr, u,bat);
  }
  // t = TT-1: chains of h1(7), h2(6); then gemm2(7) + pool + finale
  for(int k=1;k<5;k++)
    k_spmm<2><<<1250,512,0,stream>>>(rowptr,pack,ZH,Zb1,Zb2,k);
  k_g2f<<<157,256,0,stream>>>(Zb2,H1T0[(TT-1)&1],Wpk2,Bc2,wc2,c2,ZH,Zb2,u,bat,ticket,lw,lb,(float*)d_out);
}